// Round 7
// baseline (153.280 us; speedup 1.0000x reference)
//
#include <hip/hip_runtime.h>

#define D_DIM 512

typedef float f32x2 __attribute__((ext_vector_type(2)));

__device__ __forceinline__ float flog2(float x) {
    return __builtin_amdgcn_logf(x);   // v_log_f32 (= log2); inputs >= ~4e-6, no denormal wrapper
}

// ============ per-row sums: E[row] = sum_d x*log2(x). One wave/row, 4 rows/block ============
__global__ __launch_bounds__(256)
void jsd_entropy_kernel(const float* __restrict__ a,
                        const float* __restrict__ b,
                        float* __restrict__ E, int N, int M) {
    const int wave = threadIdx.x >> 6;
    const int lane = threadIdx.x & 63;
    const int row = blockIdx.x * 4 + wave;
    if (row >= N + M) return;
    const float* src = (row < N) ? (a + (size_t)row * D_DIM)
                                 : (b + (size_t)(row - N) * D_DIM);
    const float4* s4 = (const float4*)src;
    float4 v0 = s4[lane];
    float4 v1 = s4[lane + 64];
    float s = 0.f;
    s = fmaf(v0.x, flog2(v0.x), s);
    s = fmaf(v0.y, flog2(v0.y), s);
    s = fmaf(v0.z, flog2(v0.z), s);
    s = fmaf(v0.w, flog2(v0.w), s);
    s = fmaf(v1.x, flog2(v1.x), s);
    s = fmaf(v1.y, flog2(v1.y), s);
    s = fmaf(v1.z, flog2(v1.z), s);
    s = fmaf(v1.w, flog2(v1.w), s);
#pragma unroll
    for (int off = 32; off > 0; off >>= 1) s += __shfl_down(s, off, 64);
    if (lane == 0) E[row] = s;
}

// ============ main ============
// out[i,j] = 1 + 0.5*(Ea[i]+Eb[j]) - 0.5*sum_d t*log2(t), t = a_i[d]+b_j[d]
//
// Round-4 structure + HARD-REGION software pipelining. Block = 4 waves = one
// 32x32 tile x 4 INDEPENDENT d-quarters; no barrier in the main loop.
// Wave-private 8 KB LDS, double-buffered global_load_lds, own vmcnt.
// sched_barrier(0) fences between every load-block and compute-block pin the
// q+1 ds_reads one full COMPQ (~768 cy) ahead of use (round 6: scheduler sank
// them, VGPR stayed 52, pipeline never materialized). VGPR target ~112 < 128
// cap of launch_bounds(256,4). (256,8)'s 64-cap spilled acc: 845 MB scratch
// traffic (round 5) — never cap below ~110 for this body.
constexpr int DK  = 16;          // d per chunk (row = 64 B in LDS, 4 float4 slots)
constexpr int QD  = 128;         // d per wave (quarter)
constexpr int NCH = QD / DK;     // 8

// Stage 32 rows x 16 d into linear LDS [32][16] (wave-private).
// Swizzle: LDS[r][16B-slot s] = global[r][slot s ^ ((r>>2)&3)], applied by
// pre-swizzling the per-lane GLOBAL source (LDS dest must stay linear).
__device__ __forceinline__ void stageW(const float* __restrict__ g, float* lbuf, int l) {
#pragma unroll
    for (int k = 0; k < 2; ++k) {
        const int r0 = 16 * k;
        const int r  = r0 + (l >> 2);
        const int c  = (l & 3) ^ ((r >> 2) & 3);
        const float* gp = g + (size_t)r * D_DIM + 4 * c;
        __builtin_amdgcn_global_load_lds(
            (const __attribute__((address_space(1))) void*)gp,
            (__attribute__((address_space(3))) void*)(lbuf + r0 * DK),
            16, 0, 0);
    }
}

__global__ __launch_bounds__(256, 4)
void jsd_main_kernel(const float* __restrict__ a, const float* __restrict__ b,
                     const float* __restrict__ Ea, const float* __restrict__ Eb,
                     float* __restrict__ out, int N, int M) {
    __shared__ __align__(16) float lds[4][2][2][32][DK];   // [wave][buf][A/B][row][d] = 32 KB

    const int tid = threadIdx.x;
    const int w   = tid >> 6;        // wave = d-quarter
    const int l   = tid & 63;
    const int lr  = l >> 3;          // lane row group: rows 4*lr..4*lr+3
    const int lc  = l & 7;           // lane col group: cols 4*lc..4*lc+3
    const int rowBase = blockIdx.y * 32;
    const int colBase = blockIdx.x * 32;

    const float* aT = a + (size_t)rowBase * D_DIM + w * QD;
    const float* bT = b + (size_t)colBase * D_DIM + w * QD;

    float* A0 = &lds[w][0][0][0][0];
    float* B0 = &lds[w][0][1][0][0];
    float* A1 = &lds[w][1][0][0][0];
    float* B1 = &lds[w][1][1][0][0];

    f32x2 acc2[4][4];
#pragma unroll
    for (int i = 0; i < 4; ++i)
#pragma unroll
        for (int j = 0; j < 4; ++j) acc2[i][j] = (f32x2){0.f, 0.f};

    stageW(aT, A0, l);
    stageW(bT, B0, l);

#define SBAR() __builtin_amdgcn_sched_barrier(0)

#define LOADQ(qc, BUFA, BUFB, AV, BV)                                          \
    do {                                                                       \
        const int sa_ = (((qc) ^ lr) & 3) << 2;                                \
        const int sb_ = (((qc) ^ lc) & 3) << 2;                                \
        _Pragma("unroll") for (int i_ = 0; i_ < 4; ++i_) {                     \
            AV[i_] = *(const float4*)&BUFA[(4 * lr + i_) * DK + sa_];          \
            BV[i_] = *(const float4*)&BUFB[(4 * lc + i_) * DK + sb_];          \
        }                                                                      \
    } while (0)

#define COMPQ(AV, BV)                                                          \
    do {                                                                       \
        _Pragma("unroll") for (int rr_ = 0; rr_ < 4; ++rr_) {                  \
            const f32x2 a0_ = {AV[rr_].x, AV[rr_].y};                          \
            const f32x2 a1_ = {AV[rr_].z, AV[rr_].w};                          \
            _Pragma("unroll") for (int cc_ = 0; cc_ < 4; ++cc_) {              \
                f32x2 t0_ = a0_ + (f32x2){BV[cc_].x, BV[cc_].y};               \
                f32x2 t1_ = a1_ + (f32x2){BV[cc_].z, BV[cc_].w};               \
                f32x2 l0_ = {flog2(t0_.x), flog2(t0_.y)};                      \
                f32x2 l1_ = {flog2(t1_.x), flog2(t1_.y)};                      \
                acc2[rr_][cc_] = __builtin_elementwise_fma(t0_, l0_, acc2[rr_][cc_]); \
                acc2[rr_][cc_] = __builtin_elementwise_fma(t1_, l1_, acc2[rr_][cc_]); \
            }                                                                  \
        }                                                                      \
    } while (0)

// pipelined chunk: L0,L1 | C0 | L2 | C1 | L3 | C2 | C3 — every block fenced so
// the scheduler cannot sink loads back to their uses.
#define CHUNK(BUFA, BUFB)                                                      \
    do {                                                                       \
        LOADQ(0, BUFA, BUFB, avA, bvA);                                        \
        LOADQ(1, BUFA, BUFB, avB, bvB);                                        \
        SBAR();                                                                \
        COMPQ(avA, bvA);                                                       \
        SBAR();                                                                \
        LOADQ(2, BUFA, BUFB, avA, bvA);                                        \
        SBAR();                                                                \
        COMPQ(avB, bvB);                                                       \
        SBAR();                                                                \
        LOADQ(3, BUFA, BUFB, avB, bvB);                                        \
        SBAR();                                                                \
        COMPQ(avA, bvA);                                                       \
        SBAR();                                                                \
        COMPQ(avB, bvB);                                                       \
    } while (0)

    float4 avA[4], bvA[4], avB[4], bvB[4];

#pragma unroll 1
    for (int ck = 0; ck < NCH; ck += 2) {
        asm volatile("s_waitcnt vmcnt(0)" ::: "memory");   // buf0 chunk landed
        if (ck + 1 < NCH) {
            stageW(aT + (ck + 1) * DK, A1, l);             // prefetch -> buf1
            stageW(bT + (ck + 1) * DK, B1, l);
        }
        SBAR();
        CHUNK(A0, B0);

        asm volatile("s_waitcnt vmcnt(0)" ::: "memory");   // buf1 chunk landed
        if (ck + 2 < NCH) {
            stageW(aT + (ck + 2) * DK, A0, l);             // prefetch -> buf0
            stageW(bT + (ck + 2) * DK, B0, l);
        }
        SBAR();
        CHUNK(A1, B1);
    }
#undef CHUNK
#undef COMPQ
#undef LOADQ
#undef SBAR

    // -------- 4-way d-merge via LDS (two barriers, no atomics) --------
    float accs[16];
#pragma unroll
    for (int i = 0; i < 16; ++i) accs[i] = acc2[i >> 2][i & 3].x + acc2[i >> 2][i & 3].y;

    __syncthreads();                       // everyone done reading their LDS slice
    float* scratch = &lds[0][0][0][0][0];  // 8192 floats; need 4*16*65 = 4160
#pragma unroll
    for (int i = 0; i < 16; ++i)
        scratch[(w * 16 + i) * 65 + l] = accs[i];   // stride 65: conflict-free
    __syncthreads();

    // wave w combines + stores output rows 4*lr + w
    const int rr = w;
    float s[4];
#pragma unroll
    for (int cc = 0; cc < 4; ++cc) {
        float v = scratch[(0 * 16 + rr * 4 + cc) * 65 + l];
        v += scratch[(1 * 16 + rr * 4 + cc) * 65 + l];
        v += scratch[(2 * 16 + rr * 4 + cc) * 65 + l];
        v += scratch[(3 * 16 + rr * 4 + cc) * 65 + l];
        s[cc] = v;
    }
    const int row = rowBase + 4 * lr + rr;
    const float eav = Ea[row];
    const float4 eb = *(const float4*)&Eb[colBase + 4 * lc];
    const float base_v = 1.0f + 0.5f * eav;
    float4 v;
    v.x = fmaf(-0.5f, s[0], base_v + 0.5f * eb.x);
    v.y = fmaf(-0.5f, s[1], base_v + 0.5f * eb.y);
    v.z = fmaf(-0.5f, s[2], base_v + 0.5f * eb.z);
    v.w = fmaf(-0.5f, s[3], base_v + 0.5f * eb.w);
    *(float4*)(out + (size_t)row * M + colBase + 4 * lc) = v;
}

extern "C" void kernel_launch(void* const* d_in, const int* in_sizes, int n_in,
                              void* d_out, int out_size, void* d_ws, size_t ws_size,
                              hipStream_t stream) {
    const float* a = (const float*)d_in[0];
    const float* b = (const float*)d_in[1];
    const int N = in_sizes[0] / D_DIM;   // 1024
    const int M = in_sizes[1] / D_DIM;   // 1024
    float* E = (float*)d_ws;             // Ea[0..N), Eb[N..N+M)

    jsd_entropy_kernel<<<(N + M + 3) / 4, 256, 0, stream>>>(a, b, E, N, M);

    dim3 grid(M / 32, N / 32);           // 32 x 32 = 1024 blocks -> 4 blocks/CU
    jsd_main_kernel<<<grid, 256, 0, stream>>>(a, b, E, E + N, (float*)d_out, N, M);
}

// Round 9
// 106.903 us; speedup vs baseline: 1.4338x; 1.4338x over previous
//
#include <hip/hip_runtime.h>

#define D_DIM 512

typedef float f32x2 __attribute__((ext_vector_type(2)));

__device__ __forceinline__ float flog2(float x) {
    return __builtin_amdgcn_logf(x);   // v_log_f32 (= log2); inputs >= ~4e-6, no denormal wrapper
}

// ============ per-row sums: E[row] = sum_d x*log2(x). One wave/row, 4 rows/block ============
__global__ __launch_bounds__(256)
void jsd_entropy_kernel(const float* __restrict__ a,
                        const float* __restrict__ b,
                        float* __restrict__ E, int N, int M) {
    const int wave = threadIdx.x >> 6;
    const int lane = threadIdx.x & 63;
    const int row = blockIdx.x * 4 + wave;
    if (row >= N + M) return;
    const float* src = (row < N) ? (a + (size_t)row * D_DIM)
                                 : (b + (size_t)(row - N) * D_DIM);
    const float4* s4 = (const float4*)src;
    float4 v0 = s4[lane];
    float4 v1 = s4[lane + 64];
    float s = 0.f;
    s = fmaf(v0.x, flog2(v0.x), s);
    s = fmaf(v0.y, flog2(v0.y), s);
    s = fmaf(v0.z, flog2(v0.z), s);
    s = fmaf(v0.w, flog2(v0.w), s);
    s = fmaf(v1.x, flog2(v1.x), s);
    s = fmaf(v1.y, flog2(v1.y), s);
    s = fmaf(v1.z, flog2(v1.z), s);
    s = fmaf(v1.w, flog2(v1.w), s);
#pragma unroll
    for (int off = 32; off > 0; off >>= 1) s += __shfl_down(s, off, 64);
    if (lane == 0) E[row] = s;
}

// ============ main ============
// out[i,j] = 1 + 0.5*(Ea[i]+Eb[j]) - 0.5*sum_d t*log2(t), t = a_i[d]+b_j[d]
//
// Round-6 structure (best verified: 58.5 us) + hoisted staging addresses.
// Block = 4 waves = one 32x32 tile x 4 INDEPENDENT d-quarters; no barrier in
// the main loop. Wave-private 8 KB LDS, double-buffered global_load_lds, own
// vmcnt. The XOR swizzle value (r>>2)&3 is IDENTICAL for both 16-row halves
// (adding 16 rows adds 4 to r>>2, &3-invariant), so the per-lane swizzled
// global source is loop-invariant up to a += DK bump: per-chunk address math
// collapses from ~25 VALU to 2 pointer adds. Tail peeled (no in-loop guards).
// launch_bounds(256,4): cap 128; NEVER cap at 64 (R5 spill: 845 MB scratch).
// Forced pipelining is dead: region-pinning spills (R7), asm-reg pinning
// races with regalloc copies (R8 NaN). Compiler schedule is the optimum here.
constexpr int DK  = 16;          // d per chunk (row = 64 B in LDS, 4 float4 slots)
constexpr int QD  = 128;         // d per wave (quarter)
constexpr int NCH = QD / DK;     // 8

#define GLDS(gp, lp)                                                           \
    __builtin_amdgcn_global_load_lds(                                          \
        (const __attribute__((address_space(1))) void*)(gp),                   \
        (__attribute__((address_space(3))) void*)(lp), 16, 0, 0)

__global__ __launch_bounds__(256, 4)
void jsd_main_kernel(const float* __restrict__ a, const float* __restrict__ b,
                     const float* __restrict__ Ea, const float* __restrict__ Eb,
                     float* __restrict__ out, int N, int M) {
    __shared__ __align__(16) float lds[4][2][2][32][DK];   // [wave][buf][A/B][row][d] = 32 KB

    const int tid = threadIdx.x;
    const int w   = tid >> 6;        // wave = d-quarter
    const int l   = tid & 63;
    const int lr  = l >> 3;          // lane row group: rows 4*lr..4*lr+3
    const int lc  = l & 7;           // lane col group: cols 4*lc..4*lc+3
    const int rowBase = blockIdx.y * 32;
    const int colBase = blockIdx.x * 32;

    // Hoisted per-lane swizzled staging source. Lane l stages (row srow, slot
    // (l&3)^((srow>>2)&3)) of each 16-row half; swizzle value == (l>>4)&3 for
    // BOTH halves. Advance by DK floats per chunk.
    const int srow = l >> 2;                            // 0..15
    const int scol = 4 * ((l & 3) ^ ((l >> 4) & 3));    // swizzled 16B slot
    const float* gA = a + (size_t)(rowBase + srow) * D_DIM + w * QD + scol;
    const float* gB = b + (size_t)(colBase + srow) * D_DIM + w * QD + scol;

    float* A0 = &lds[w][0][0][0][0];
    float* B0 = &lds[w][0][1][0][0];
    float* A1 = &lds[w][1][0][0][0];
    float* B1 = &lds[w][1][1][0][0];

    f32x2 acc2[4][4];
#pragma unroll
    for (int i = 0; i < 4; ++i)
#pragma unroll
        for (int j = 0; j < 4; ++j) acc2[i][j] = (f32x2){0.f, 0.f};

    GLDS(gA, A0); GLDS(gA + 16 * D_DIM, A0 + 16 * DK);
    GLDS(gB, B0); GLDS(gB + 16 * D_DIM, B0 + 16 * DK);

#define LOADQ(qc, BUFA, BUFB, AV, BV)                                          \
    do {                                                                       \
        const int sa_ = (((qc) ^ lr) & 3) << 2;                                \
        const int sb_ = (((qc) ^ lc) & 3) << 2;                                \
        _Pragma("unroll") for (int i_ = 0; i_ < 4; ++i_) {                     \
            AV[i_] = *(const float4*)&BUFA[(4 * lr + i_) * DK + sa_];          \
            BV[i_] = *(const float4*)&BUFB[(4 * lc + i_) * DK + sb_];          \
        }                                                                      \
    } while (0)

#define COMPQ(AV, BV)                                                          \
    do {                                                                       \
        _Pragma("unroll") for (int rr_ = 0; rr_ < 4; ++rr_) {                  \
            const f32x2 a0_ = {AV[rr_].x, AV[rr_].y};                          \
            const f32x2 a1_ = {AV[rr_].z, AV[rr_].w};                          \
            _Pragma("unroll") for (int cc_ = 0; cc_ < 4; ++cc_) {              \
                f32x2 t0_ = a0_ + (f32x2){BV[cc_].x, BV[cc_].y};               \
                f32x2 t1_ = a1_ + (f32x2){BV[cc_].z, BV[cc_].w};               \
                f32x2 l0_ = {flog2(t0_.x), flog2(t0_.y)};                      \
                f32x2 l1_ = {flog2(t1_.x), flog2(t1_.y)};                      \
                acc2[rr_][cc_] = __builtin_elementwise_fma(t0_, l0_, acc2[rr_][cc_]); \
                acc2[rr_][cc_] = __builtin_elementwise_fma(t1_, l1_, acc2[rr_][cc_]); \
            }                                                                  \
        }                                                                      \
    } while (0)

// software-pipelined q loop (round-6 shape; compiler-scheduled)
#define CHUNK(AW, BW)                                                          \
    do {                                                                       \
        LOADQ(0, AW, BW, avA, bvA);                                            \
        LOADQ(1, AW, BW, avB, bvB);                                            \
        COMPQ(avA, bvA);                                                       \
        LOADQ(2, AW, BW, avA, bvA);                                            \
        COMPQ(avB, bvB);                                                       \
        LOADQ(3, AW, BW, avB, bvB);                                            \
        COMPQ(avA, bvA);                                                       \
        COMPQ(avB, bvB);                                                       \
    } while (0)

#define WAITSTAGE() asm volatile("s_waitcnt vmcnt(0)" ::: "memory")

    float4 avA[4], bvA[4], avB[4], bvB[4];

#pragma unroll 1
    for (int ck = 0; ck < NCH - 2; ck += 2) {
        WAITSTAGE();                                   // buf0 chunk landed
        gA += DK; gB += DK;
        GLDS(gA, A1); GLDS(gA + 16 * D_DIM, A1 + 16 * DK);   // prefetch -> buf1
        GLDS(gB, B1); GLDS(gB + 16 * D_DIM, B1 + 16 * DK);
        __builtin_amdgcn_sched_barrier(0);             // keep load-issue ahead of compute
        CHUNK(A0, B0);

        WAITSTAGE();                                   // buf1 chunk landed
        gA += DK; gB += DK;
        GLDS(gA, A0); GLDS(gA + 16 * D_DIM, A0 + 16 * DK);   // prefetch -> buf0
        GLDS(gB, B0); GLDS(gB + 16 * D_DIM, B0 + 16 * DK);
        __builtin_amdgcn_sched_barrier(0);
        CHUNK(A1, B1);
    }
    // peeled tail: chunk NCH-2 (prefetch last), chunk NCH-1 (no prefetch)
    WAITSTAGE();
    gA += DK; gB += DK;
    GLDS(gA, A1); GLDS(gA + 16 * D_DIM, A1 + 16 * DK);
    GLDS(gB, B1); GLDS(gB + 16 * D_DIM, B1 + 16 * DK);
    __builtin_amdgcn_sched_barrier(0);
    CHUNK(A0, B0);
    WAITSTAGE();
    CHUNK(A1, B1);

#undef CHUNK
#undef COMPQ
#undef LOADQ
#undef WAITSTAGE

    // -------- 4-way d-merge via LDS (two barriers, no atomics) --------
    float accs[16];
#pragma unroll
    for (int i = 0; i < 16; ++i) accs[i] = acc2[i >> 2][i & 3].x + acc2[i >> 2][i & 3].y;

    __syncthreads();                       // everyone done reading their LDS slice
    float* scratch = &lds[0][0][0][0][0];  // 8192 floats; need 4*16*65 = 4160
#pragma unroll
    for (int i = 0; i < 16; ++i)
        scratch[(w * 16 + i) * 65 + l] = accs[i];   // stride 65: conflict-free
    __syncthreads();

    // wave w combines + stores output rows 4*lr + w
    const int rr = w;
    float s[4];
#pragma unroll
    for (int cc = 0; cc < 4; ++cc) {
        float v = scratch[(0 * 16 + rr * 4 + cc) * 65 + l];
        v += scratch[(1 * 16 + rr * 4 + cc) * 65 + l];
        v += scratch[(2 * 16 + rr * 4 + cc) * 65 + l];
        v += scratch[(3 * 16 + rr * 4 + cc) * 65 + l];
        s[cc] = v;
    }
    const int row = rowBase + 4 * lr + rr;
    const float eav = Ea[row];
    const float4 eb = *(const float4*)&Eb[colBase + 4 * lc];
    const float base_v = 1.0f + 0.5f * eav;
    float4 v;
    v.x = fmaf(-0.5f, s[0], base_v + 0.5f * eb.x);
    v.y = fmaf(-0.5f, s[1], base_v + 0.5f * eb.y);
    v.z = fmaf(-0.5f, s[2], base_v + 0.5f * eb.z);
    v.w = fmaf(-0.5f, s[3], base_v + 0.5f * eb.w);
    *(float4*)(out + (size_t)row * M + colBase + 4 * lc) = v;
}

extern "C" void kernel_launch(void* const* d_in, const int* in_sizes, int n_in,
                              void* d_out, int out_size, void* d_ws, size_t ws_size,
                              hipStream_t stream) {
    const float* a = (const float*)d_in[0];
    const float* b = (const float*)d_in[1];
    const int N = in_sizes[0] / D_DIM;   // 1024
    const int M = in_sizes[1] / D_DIM;   // 1024
    float* E = (float*)d_ws;             // Ea[0..N), Eb[N..N+M)

    jsd_entropy_kernel<<<(N + M + 3) / 4, 256, 0, stream>>>(a, b, E, N, M);

    dim3 grid(M / 32, N / 32);           // 32 x 32 = 1024 blocks -> 4 blocks/CU
    jsd_main_kernel<<<grid, 256, 0, stream>>>(a, b, E, E + N, (float*)d_out, N, M);
}